// Round 1
// baseline (254.650 us; speedup 1.0000x reference)
//
#include <hip/hip_runtime.h>

typedef __attribute__((ext_vector_type(8))) short short8;
typedef __attribute__((ext_vector_type(4))) float floatx4;

__device__ __forceinline__ unsigned short f2bf(float f) {
    unsigned int u = __builtin_bit_cast(unsigned int, f);
    u += 0x7FFFu + ((u >> 16) & 1u);   // round-to-nearest-even (inputs are finite/sane)
    return (unsigned short)(u >> 16);
}

#define S_LEN 2048
#define NH 12
#define HD 64
#define EMB 768
#define E3 2304

// ---------------- convert x (fp32 -> bf16), 4 elems/thread ----------------
__global__ __launch_bounds__(256) void conv_x(const float* __restrict__ x,
                                              ushort* __restrict__ xb) {
    int i = (blockIdx.x * 256 + threadIdx.x) * 4;
    float4 f = *(const float4*)(x + i);
    ushort4 o;
    o.x = f2bf(f.x); o.y = f2bf(f.y); o.z = f2bf(f.z); o.w = f2bf(f.w);
    *(ushort4*)(xb + i) = o;
}

// -------- transpose + convert W: Wt[n][k] = W[k][n], bf16 out --------
__global__ __launch_bounds__(256) void conv_w(const float* __restrict__ W,
                                              ushort* __restrict__ Wt) {
    __shared__ float tile[32][33];
    int n0 = blockIdx.x * 32, k0 = blockIdx.y * 32;
    int tx = threadIdx.x, ty = threadIdx.y;           // block (32,8)
    for (int i = 0; i < 4; i++)
        tile[ty + i * 8][tx] = W[(size_t)(k0 + ty + i * 8) * E3 + n0 + tx];
    __syncthreads();
    for (int i = 0; i < 4; i++)
        Wt[(size_t)(n0 + ty + i * 8) * EMB + k0 + tx] = f2bf(tile[tx][ty + i * 8]);
}

// ---------------- QKV GEMM: [8192,768] x [768,2304] + bias ----------------
// 128x128 tile, 4 waves (2x2), each wave 64x64 = 4x4 MFMA tiles, BK=64.
// Epilogue: Q,K -> [b][h][s][d] bf16 ; V -> transposed [b][h][d][s] bf16.
__global__ __launch_bounds__(256) void qkv_gemm(const ushort* __restrict__ Xb,
                                                const ushort* __restrict__ Wt,
                                                const float* __restrict__ bias,
                                                ushort* __restrict__ Q,
                                                ushort* __restrict__ K,
                                                ushort* __restrict__ Vt) {
    __shared__ ushort Ald[128 * 72];
    __shared__ ushort Bld[128 * 72];
    int tid  = threadIdx.x;
    int wave = tid >> 6, lane = tid & 63;
    int l15 = lane & 15, quad = lane >> 4;
    int wm = wave >> 1, wn = wave & 1;
    int m0 = blockIdx.x * 128, n0 = blockIdx.y * 128;

    floatx4 acc[4][4] = {};

    for (int k0 = 0; k0 < EMB; k0 += 64) {
        __syncthreads();
        // stage A (128x64) and B (128x64), 16B chunks, 4 chunks/thread each
        for (int i = 0; i < 4; i++) {
            int c = tid + i * 256;
            int row = c >> 3, off = (c & 7) * 8;
            *(uint4*)&Ald[row * 72 + off] =
                *(const uint4*)&Xb[(size_t)(m0 + row) * EMB + k0 + off];
            *(uint4*)&Bld[row * 72 + off] =
                *(const uint4*)&Wt[(size_t)(n0 + row) * EMB + k0 + off];
        }
        __syncthreads();
        for (int kk = 0; kk < 64; kk += 32) {
            short8 af[4], bf[4];
            for (int mi = 0; mi < 4; mi++)
                af[mi] = *(const short8*)&Ald[(wm * 64 + mi * 16 + l15) * 72 + kk + quad * 8];
            for (int ni = 0; ni < 4; ni++)
                bf[ni] = *(const short8*)&Bld[(wn * 64 + ni * 16 + l15) * 72 + kk + quad * 8];
            for (int mi = 0; mi < 4; mi++)
                for (int ni = 0; ni < 4; ni++)
                    acc[mi][ni] = __builtin_amdgcn_mfma_f32_16x16x32_bf16(
                        af[mi], bf[ni], acc[mi][ni], 0, 0, 0);
        }
    }

    // epilogue: bias + scatter into Q/K/Vt (bf16)
    int seg = n0 / EMB;  // 0=q, 1=k, 2=v (block-uniform: 768/128=6 blocks per segment)
    for (int ni = 0; ni < 4; ni++) {
        int n = n0 + wn * 64 + ni * 16 + l15;
        float bv = bias[n];
        int nn = n - seg * EMB;
        int h = nn >> 6, d = nn & 63;
        for (int mi = 0; mi < 4; mi++) {
            for (int r = 0; r < 4; r++) {
                int m = m0 + wm * 64 + mi * 16 + quad * 4 + r;
                int b = m >> 11, s = m & 2047;
                ushort v = f2bf(acc[mi][ni][r] + bv);
                if (seg == 0)
                    Q[(((size_t)b * NH + h) * S_LEN + s) * HD + d] = v;
                else if (seg == 1)
                    K[(((size_t)b * NH + h) * S_LEN + s) * HD + d] = v;
                else
                    Vt[(((size_t)b * NH + h) * HD + d) * S_LEN + s] = v;
            }
        }
    }
}

// ---------------- Attention: ReLU(scale * Q K^T, causal) @ V ----------------
// One block per (bh, q-tile of 128). k-tiles of 64. 4 waves 2x2.
__global__ __launch_bounds__(256) void attn(const ushort* __restrict__ Q,
                                            const ushort* __restrict__ K,
                                            const ushort* __restrict__ Vt,
                                            float* __restrict__ out) {
    __shared__ ushort Qld[128 * 72];
    __shared__ ushort Kld[64 * 72];
    __shared__ ushort Vld[64 * 72];   // Vld[d][k_row] (pre-transposed V)
    __shared__ ushort Pld[128 * 72];  // P[q][k_row] bf16

    int bid = blockIdx.x;
    int bh  = bid >> 4;
    int qt  = 15 - (bid & 15);        // reversed so big tiles launch first
    int tid  = threadIdx.x;
    int wave = tid >> 6, lane = tid & 63;
    int l15 = lane & 15, quad = lane >> 4;
    int wm = wave >> 1, wn = wave & 1;

    // stage Q tile (128x64)
    for (int i = 0; i < 4; i++) {
        int c = tid + i * 256;
        int row = c >> 3, off = (c & 7) * 8;
        *(uint4*)&Qld[row * 72 + off] =
            *(const uint4*)&Q[((size_t)bh * S_LEN + qt * 128 + row) * HD + off];
    }

    floatx4 acco[4][2] = {};
    int njt = 2 * qt + 2;
    for (int jt = 0; jt < njt; jt++) {
        __syncthreads();  // prev-iter K/V/P reads done (also covers Q staging, iter 0)
        // stage K tile (64 rows x 64 d) and Vt tile (64 d x 64 k), 2 chunks/thread
        for (int i = 0; i < 2; i++) {
            int c = tid + i * 256;
            int row = c >> 3, off = (c & 7) * 8;
            *(uint4*)&Kld[row * 72 + off] =
                *(const uint4*)&K[((size_t)bh * S_LEN + jt * 64 + row) * HD + off];
            *(uint4*)&Vld[row * 72 + off] =
                *(const uint4*)&Vt[((size_t)bh * HD + row) * S_LEN + jt * 64 + off];
        }
        __syncthreads();

        // S = Q K^T  (M=128, N=64, K=64); wave: 4x2 tiles
        floatx4 accs[4][2] = {};
        for (int kk = 0; kk < 64; kk += 32) {
            short8 af[4], bfr[2];
            for (int mi = 0; mi < 4; mi++)
                af[mi] = *(const short8*)&Qld[(wm * 64 + mi * 16 + l15) * 72 + kk + quad * 8];
            for (int ni = 0; ni < 2; ni++)
                bfr[ni] = *(const short8*)&Kld[(wn * 32 + ni * 16 + l15) * 72 + kk + quad * 8];
            for (int mi = 0; mi < 4; mi++)
                for (int ni = 0; ni < 2; ni++)
                    accs[mi][ni] = __builtin_amdgcn_mfma_f32_16x16x32_bf16(
                        af[mi], bfr[ni], accs[mi][ni], 0, 0, 0);
        }

        // scale + causal mask + ReLU -> P (bf16) in LDS (C-layout -> A-layout round trip)
        bool diag = (jt >= 2 * qt);
        for (int mi = 0; mi < 4; mi++) {
            for (int ni = 0; ni < 2; ni++) {
                int k_in = wn * 32 + ni * 16 + l15;
                for (int r = 0; r < 4; r++) {
                    int q_in = wm * 64 + mi * 16 + quad * 4 + r;
                    float v = fmaxf(accs[mi][ni][r] * 0.125f, 0.0f);
                    if (diag && (jt * 64 + k_in > qt * 128 + q_in)) v = 0.0f;
                    Pld[q_in * 72 + k_in] = f2bf(v);
                }
            }
        }
        __syncthreads();

        // O += P V  (M=128, N=64 (d), K=64); wave: 4x2 tiles
        for (int ks = 0; ks < 64; ks += 32) {
            short8 pf[4], vf[2];
            for (int mi = 0; mi < 4; mi++)
                pf[mi] = *(const short8*)&Pld[(wm * 64 + mi * 16 + l15) * 72 + ks + quad * 8];
            for (int ni = 0; ni < 2; ni++)
                vf[ni] = *(const short8*)&Vld[(wn * 32 + ni * 16 + l15) * 72 + ks + quad * 8];
            for (int mi = 0; mi < 4; mi++)
                for (int ni = 0; ni < 2; ni++)
                    acco[mi][ni] = __builtin_amdgcn_mfma_f32_16x16x32_bf16(
                        pf[mi], vf[ni], acco[mi][ni], 0, 0, 0);
        }
    }

    // epilogue: out[b][s][h][d] fp32
    int b = bh / NH, h = bh % NH;
    for (int mi = 0; mi < 4; mi++) {
        for (int ni = 0; ni < 2; ni++) {
            int d = wn * 32 + ni * 16 + l15;
            for (int r = 0; r < 4; r++) {
                int s = qt * 128 + wm * 64 + mi * 16 + quad * 4 + r;
                out[(((size_t)b * S_LEN + s) * NH + h) * HD + d] = acco[mi][ni][r];
            }
        }
    }
}

extern "C" void kernel_launch(void* const* d_in, const int* in_sizes, int n_in,
                              void* d_out, int out_size, void* d_ws, size_t ws_size,
                              hipStream_t stream) {
    const float* x    = (const float*)d_in[0];   // [4,2048,768]
    const float* W    = (const float*)d_in[1];   // [768,2304]
    const float* bias = (const float*)d_in[2];   // [2304]
    float* out = (float*)d_out;                  // [4,2048,768] fp32

    char* ws = (char*)d_ws;
    const size_t SZ_X  = (size_t)8192 * EMB * 2;       // 12,582,912
    const size_t SZ_W  = (size_t)E3 * EMB * 2;         //  3,538,944
    const size_t SZ_H  = (size_t)4 * NH * S_LEN * HD * 2;  // 12,582,912 each
    ushort* Xb = (ushort*)(ws);
    ushort* Wt = (ushort*)(ws + SZ_X);
    ushort* Qb = (ushort*)(ws + SZ_X + SZ_W);
    ushort* Kb = (ushort*)(ws + SZ_X + SZ_W + SZ_H);
    ushort* Vt = (ushort*)(ws + SZ_X + SZ_W + 2 * SZ_H);

    conv_x<<<dim3(8192 * EMB / (256 * 4)), dim3(256), 0, stream>>>(x, Xb);
    conv_w<<<dim3(E3 / 32, EMB / 32), dim3(32, 8), 0, stream>>>(W, Wt);
    qkv_gemm<<<dim3(64, 18), dim3(256), 0, stream>>>(Xb, Wt, bias, Qb, Kb, Vt);
    attn<<<dim3(4 * NH * 16), dim3(256), 0, stream>>>(Qb, Kb, Vt, out);
}

// Round 2
// 202.833 us; speedup vs baseline: 1.2555x; 1.2555x over previous
//
#include <hip/hip_runtime.h>

typedef __attribute__((ext_vector_type(8))) short short8;
typedef __attribute__((ext_vector_type(4))) short short4v;
typedef __attribute__((ext_vector_type(4))) float floatx4;
typedef __attribute__((ext_vector_type(2))) unsigned int uint2v;

#define S_LEN 2048
#define NH 12
#define HD 64
#define EMB 768
#define E3 2304
#define N_ITEMS 768

__device__ __forceinline__ unsigned short f2bf(float f) {
    unsigned int u = __builtin_bit_cast(unsigned int, f);
    u += 0x7FFFu + ((u >> 16) & 1u);   // RNE
    return (unsigned short)(u >> 16);
}

__device__ __forceinline__ unsigned int pack2bf(float a, float b) {
#if __has_builtin(__builtin_amdgcn_cvt_pk_bf16_f32)
    typedef __attribute__((ext_vector_type(2))) short short2v;
    short2v r = __builtin_amdgcn_cvt_pk_bf16_f32(a, b);
    return __builtin_bit_cast(unsigned int, r);
#else
    return (unsigned int)f2bf(a) | ((unsigned int)f2bf(b) << 16);
#endif
}

// async global->LDS, 16B per lane; LDS dest = wave-uniform base + lane*16
__device__ __forceinline__ void gl_lds16(const void* g, void* l) {
    __builtin_amdgcn_global_load_lds(
        (const __attribute__((address_space(1))) unsigned int*)g,
        (__attribute__((address_space(3))) unsigned int*)l, 16, 0, 0);
}

// ---------------- convert x (fp32 -> bf16); also zero the attn work counter --
__global__ __launch_bounds__(256) void conv_x(const float* __restrict__ x,
                                              ushort* __restrict__ xb,
                                              int* __restrict__ counter) {
    if (blockIdx.x == 0 && threadIdx.x == 0) *counter = 0;
    int i = (blockIdx.x * 256 + threadIdx.x) * 4;
    float4 f = *(const float4*)(x + i);
    ushort4 o;
    o.x = f2bf(f.x); o.y = f2bf(f.y); o.z = f2bf(f.z); o.w = f2bf(f.w);
    *(ushort4*)(xb + i) = o;
}

// -------- transpose + convert W: Wt[n][k] = W[k][n], bf16 out --------
__global__ __launch_bounds__(256) void conv_w(const float* __restrict__ W,
                                              ushort* __restrict__ Wt) {
    __shared__ float tile[32][33];
    int n0 = blockIdx.x * 32, k0 = blockIdx.y * 32;
    int tx = threadIdx.x, ty = threadIdx.y;           // block (32,8)
    for (int i = 0; i < 4; i++)
        tile[ty + i * 8][tx] = W[(size_t)(k0 + ty + i * 8) * E3 + n0 + tx];
    __syncthreads();
    for (int i = 0; i < 4; i++)
        Wt[(size_t)(n0 + ty + i * 8) * EMB + k0 + tx] = f2bf(tile[tx][ty + i * 8]);
}

// ---------------- QKV GEMM: [8192,768] x [768,2304] + bias ----------------
// 128x128 tile, BK=64, gl_lds staging into XOR-swizzled unpadded LDS (m97 style).
__global__ __launch_bounds__(256) void qkv_gemm(const ushort* __restrict__ Xb,
                                                const ushort* __restrict__ Wt,
                                                const float* __restrict__ bias,
                                                ushort* __restrict__ Q,
                                                ushort* __restrict__ K,
                                                ushort* __restrict__ Vt) {
    __shared__ ushort Ald[128 * 64];
    __shared__ ushort Bld[128 * 64];
    int tid  = threadIdx.x;
    int wv = tid >> 6, lane = tid & 63;
    int l15 = lane & 15, quad = lane >> 4;
    int r8 = lane >> 3, cc = lane & 7;
    int wm = wv >> 1, wn = wv & 1;
    int m0 = blockIdx.x * 128, n0 = blockIdx.y * 128;

    floatx4 acc[4][4] = {};

    for (int k0 = 0; k0 < EMB; k0 += 64) {
        __syncthreads();
        for (int i = 0; i < 4; i++) {
            int row = wv * 32 + i * 8 + r8;      // row & 7 == r8
            int gc  = cc ^ r8;                   // swizzled source chunk
            gl_lds16(Xb + (size_t)(m0 + row) * EMB + k0 + gc * 8,
                     (char*)Ald + (wv * 32 + i * 8) * 128);
            gl_lds16(Wt + (size_t)(n0 + row) * EMB + k0 + gc * 8,
                     (char*)Bld + (wv * 32 + i * 8) * 128);
        }
        __syncthreads();
        for (int ch = 0; ch < 2; ch++) {
            int sw = ((ch * 4 + quad) ^ (l15 & 7)) * 16;
            short8 af[4], bf[4];
            for (int mi = 0; mi < 4; mi++)
                af[mi] = *(const short8*)((const char*)Ald + (wm * 64 + mi * 16 + l15) * 128 + sw);
            for (int ni = 0; ni < 4; ni++)
                bf[ni] = *(const short8*)((const char*)Bld + (wn * 64 + ni * 16 + l15) * 128 + sw);
            for (int mi = 0; mi < 4; mi++)
                for (int ni = 0; ni < 4; ni++)
                    acc[mi][ni] = __builtin_amdgcn_mfma_f32_16x16x32_bf16(
                        af[mi], bf[ni], acc[mi][ni], 0, 0, 0);
        }
    }

    // epilogue: bias + scatter into Q/K/Vt (bf16)
    int seg = n0 / EMB;  // 0=q, 1=k, 2=v (block-uniform)
    for (int ni = 0; ni < 4; ni++) {
        int n = n0 + wn * 64 + ni * 16 + l15;
        float bv = bias[n];
        int nn = n - seg * EMB;
        int h = nn >> 6, d = nn & 63;
        for (int mi = 0; mi < 4; mi++) {
            for (int r = 0; r < 4; r++) {
                int m = m0 + wm * 64 + mi * 16 + quad * 4 + r;
                int b = m >> 11, s = m & 2047;
                ushort v = f2bf(acc[mi][ni][r] + bv);
                if (seg == 0)
                    Q[(((size_t)b * NH + h) * S_LEN + s) * HD + d] = v;
                else if (seg == 1)
                    K[(((size_t)b * NH + h) * S_LEN + s) * HD + d] = v;
                else
                    Vt[(((size_t)b * NH + h) * HD + d) * S_LEN + s] = v;
            }
        }
    }
}

// ---------------- Attention: ReLU(scale * Q K^T, causal) @ V ----------------
// Persistent blocks + atomic queue (items cost-descending). Per item: q-tile 128,
// k-tiles of 64, double-buffered gl_lds K/V staging (1 barrier/iter).
// S^T = K·Q^T via 16x16x32 (C col = q = l15); P packed in-register straight into
// 16x16x16 PV MFMA A-operand (layouts match; no LDS round-trip, no mid barrier).
__global__ __launch_bounds__(256) void attn(const ushort* __restrict__ Q,
                                            const ushort* __restrict__ K,
                                            const ushort* __restrict__ Vt,
                                            float* __restrict__ out,
                                            int* __restrict__ counter) {
    __shared__ ushort Kld[2][64 * 64];
    __shared__ ushort Vld[2][64 * 64];
    __shared__ int s_item;
    int tid = threadIdx.x;
    int w = tid >> 6, lane = tid & 63;
    int l15 = lane & 15, quad = lane >> 4;
    int r8 = lane >> 3, cc = lane & 7;

    while (true) {
        if (tid == 0) s_item = atomicAdd(counter, 1);
        __syncthreads();
        int it = s_item;
        __syncthreads();
        if (it >= N_ITEMS) break;
        int qt = 15 - it / 48;          // cost-descending
        int bh = it % 48;

        const ushort* Qbase = Q + ((size_t)bh * S_LEN + qt * 128) * HD;
        const ushort* Kbase = K + (size_t)bh * S_LEN * HD;
        const ushort* Vbase = Vt + (size_t)bh * HD * S_LEN;

        // Q fragments in registers (B-operand layout: n=q=l15, k=d=quad*8+j)
        short8 qf[2][2];
        for (int nq = 0; nq < 2; nq++)
            for (int ch = 0; ch < 2; ch++)
                qf[nq][ch] = *(const short8*)(Qbase + (size_t)(w * 32 + nq * 16 + l15) * HD
                                              + ch * 32 + quad * 8);

        floatx4 acco[2][4] = {};
        int njt = 2 * qt + 2;

        // stage jt=0 into buffer 0
        {
            const ushort* Kt = Kbase;
            const ushort* Vb = Vbase;
            for (int i = 0; i < 2; i++) {
                int row = w * 16 + i * 8 + r8;
                int gc  = cc ^ r8;
                gl_lds16(Kt + (size_t)row * HD + gc * 8,
                         (char*)Kld[0] + (w * 16 + i * 8) * 128);
                gl_lds16(Vb + (size_t)row * S_LEN + gc * 8,
                         (char*)Vld[0] + (w * 16 + i * 8) * 128);
            }
        }
        int p = 0;
        for (int jt = 0; jt < njt; jt++) {
            __syncthreads();   // buf[p] staged (vmcnt drained at barrier)
            if (jt + 1 < njt) {
                const ushort* Kt = Kbase + (size_t)(jt + 1) * 64 * HD;
                const ushort* Vb = Vbase + (size_t)(jt + 1) * 64;
                for (int i = 0; i < 2; i++) {
                    int row = w * 16 + i * 8 + r8;
                    int gc  = cc ^ r8;
                    gl_lds16(Kt + (size_t)row * HD + gc * 8,
                             (char*)Kld[p ^ 1] + (w * 16 + i * 8) * 128);
                    gl_lds16(Vb + (size_t)row * S_LEN + gc * 8,
                             (char*)Vld[p ^ 1] + (w * 16 + i * 8) * 128);
                }
            }

            // S^T = K·Q^T : M=64 (k-rows), N=32 (this wave's q), K=64 (d)
            floatx4 st[4][2] = {};
            for (int ch = 0; ch < 2; ch++) {
                int sw = ((ch * 4 + quad) ^ (l15 & 7)) * 16;
                short8 kf[4];
                for (int mk = 0; mk < 4; mk++)
                    kf[mk] = *(const short8*)((const char*)Kld[p] + (mk * 16 + l15) * 128 + sw);
                for (int mk = 0; mk < 4; mk++)
                    for (int nq = 0; nq < 2; nq++)
                        st[mk][nq] = __builtin_amdgcn_mfma_f32_16x16x32_bf16(
                            kf[mk], qf[nq][ch], st[mk][nq], 0, 0, 0);
            }

            // scale + ReLU + causal mask + pack to bf16 (PV A-frag layout)
            unsigned int pk[4][2][2];
            bool diag = (jt >= 2 * qt);
            for (int mk = 0; mk < 4; mk++) {
                for (int nq = 0; nq < 2; nq++) {
                    float e[4];
                    for (int r = 0; r < 4; r++)
                        e[r] = fmaxf(st[mk][nq][r] * 0.125f, 0.0f);
                    if (diag) {
                        int kg = jt * 64 + mk * 16 + quad * 4;
                        int qg = qt * 128 + w * 32 + nq * 16 + l15;
                        for (int r = 0; r < 4; r++)
                            if (kg + r > qg) e[r] = 0.0f;
                    }
                    pk[mk][nq][0] = pack2bf(e[0], e[1]);
                    pk[mk][nq][1] = pack2bf(e[2], e[3]);
                }
            }

            // O += P·V via 16x16x16 (A = pk, no shuffle; B = V from LDS)
            for (int mk = 0; mk < 4; mk++) {
                short4v vf[4];
                for (int ni = 0; ni < 4; ni++) {
                    int c2 = (mk * 2 + (quad >> 1)) ^ (l15 & 7);
                    vf[ni] = *(const short4v*)((const char*)Vld[p] + (ni * 16 + l15) * 128
                                               + c2 * 16 + (quad & 1) * 8);
                }
                for (int mi = 0; mi < 2; mi++) {
                    short4v a = __builtin_bit_cast(short4v,
                                 (uint2v){pk[mk][mi][0], pk[mk][mi][1]});
                    for (int ni = 0; ni < 4; ni++)
                        acco[mi][ni] = __builtin_amdgcn_mfma_f32_16x16x16bf16_1k(
                            a, vf[ni], acco[mi][ni], 0, 0, 0);
                }
            }
            p ^= 1;
        }

        // epilogue: out[b][s][h][d] fp32
        int b = bh / NH, h = bh % NH;
        for (int mi = 0; mi < 2; mi++) {
            for (int ni = 0; ni < 4; ni++) {
                int d = ni * 16 + l15;
                for (int r = 0; r < 4; r++) {
                    int s = qt * 128 + w * 32 + mi * 16 + quad * 4 + r;
                    out[((size_t)(b * S_LEN + s)) * EMB + h * HD + d] = acco[mi][ni][r];
                }
            }
        }
        __syncthreads();  // all waves done with buffers before next item's staging
    }
}

extern "C" void kernel_launch(void* const* d_in, const int* in_sizes, int n_in,
                              void* d_out, int out_size, void* d_ws, size_t ws_size,
                              hipStream_t stream) {
    const float* x    = (const float*)d_in[0];   // [4,2048,768]
    const float* W    = (const float*)d_in[1];   // [768,2304]
    const float* bias = (const float*)d_in[2];   // [2304]
    float* out = (float*)d_out;                  // [4,2048,768] fp32

    char* ws = (char*)d_ws;
    const size_t SZ_X = (size_t)8192 * EMB * 2;
    const size_t SZ_W = (size_t)E3 * EMB * 2;
    const size_t SZ_H = (size_t)4 * NH * S_LEN * HD * 2;
    ushort* Xb = (ushort*)(ws);
    ushort* Wt = (ushort*)(ws + SZ_X);
    ushort* Qb = (ushort*)(ws + SZ_X + SZ_W);
    ushort* Kb = (ushort*)(ws + SZ_X + SZ_W + SZ_H);
    ushort* Vt = (ushort*)(ws + SZ_X + SZ_W + 2 * SZ_H);
    int* counter = (int*)(ws + SZ_X + SZ_W + 3 * SZ_H);

    conv_x<<<dim3(8192 * EMB / (256 * 4)), dim3(256), 0, stream>>>(x, Xb, counter);
    conv_w<<<dim3(E3 / 32, EMB / 32), dim3(32, 8), 0, stream>>>(W, Wt);
    qkv_gemm<<<dim3(64, 18), dim3(256), 0, stream>>>(Xb, Wt, bias, Qb, Kb, Vt);
    attn<<<dim3(512), dim3(256), 0, stream>>>(Qb, Kb, Vt, out, counter);
}

// Round 3
// 187.551 us; speedup vs baseline: 1.3578x; 1.0815x over previous
//
#include <hip/hip_runtime.h>

typedef __attribute__((ext_vector_type(8))) short short8;
typedef __attribute__((ext_vector_type(4))) short short4v;
typedef __attribute__((ext_vector_type(4))) float floatx4;
typedef __attribute__((ext_vector_type(2))) unsigned int uint2v;

#define S_LEN 2048
#define NH 12
#define HD 64
#define EMB 768
#define E3 2304
#define N_ITEMS 768

__device__ __forceinline__ unsigned short f2bf(float f) {
    unsigned int u = __builtin_bit_cast(unsigned int, f);
    u += 0x7FFFu + ((u >> 16) & 1u);   // RNE
    return (unsigned short)(u >> 16);
}

__device__ __forceinline__ unsigned int pack2bf(float a, float b) {
#if __has_builtin(__builtin_amdgcn_cvt_pk_bf16_f32)
    typedef __attribute__((ext_vector_type(2))) short short2v;
    short2v r = __builtin_amdgcn_cvt_pk_bf16_f32(a, b);
    return __builtin_bit_cast(unsigned int, r);
#else
    return (unsigned int)f2bf(a) | ((unsigned int)f2bf(b) << 16);
#endif
}

// async global->LDS, 16B/lane; LDS dest = wave-uniform base + lane*16
__device__ __forceinline__ void gl_lds16(const void* g, void* l) {
    __builtin_amdgcn_global_load_lds(
        (const __attribute__((address_space(1))) unsigned int*)g,
        (__attribute__((address_space(3))) unsigned int*)l, 16, 0, 0);
}

// ------------- fused input conversion: x->bf16, W->Wt bf16; zero counter -----
__global__ __launch_bounds__(256) void conv_fused(const float* __restrict__ x,
                                                  ushort* __restrict__ xb,
                                                  const float* __restrict__ W,
                                                  ushort* __restrict__ Wt,
                                                  int* __restrict__ counter) {
    int tid = threadIdx.x;
    if (blockIdx.x == 0 && tid == 0) *counter = 0;
    if (blockIdx.x < 6144) {                      // x: 8192*768 elems / 4 per thread
        int i = (blockIdx.x * 256 + tid) * 4;
        float4 f = *(const float4*)(x + i);
        ushort4 o;
        o.x = f2bf(f.x); o.y = f2bf(f.y); o.z = f2bf(f.z); o.w = f2bf(f.w);
        *(ushort4*)(xb + i) = o;
    } else {                                      // W transpose: 72 x 24 tiles of 32x32
        __shared__ float tile[32][33];
        int b2 = blockIdx.x - 6144;
        int n0 = (b2 % 72) * 32, k0 = (b2 / 72) * 32;
        int tx = tid & 31, ty = tid >> 5;
        for (int i = 0; i < 4; i++)
            tile[ty + i * 8][tx] = W[(size_t)(k0 + ty + i * 8) * E3 + n0 + tx];
        __syncthreads();
        for (int i = 0; i < 4; i++)
            Wt[(size_t)(n0 + ty + i * 8) * EMB + k0 + tx] = f2bf(tile[tx][ty + i * 8]);
    }
}

// ---------------- QKV GEMM: [8192,768] x [768,2304] + bias ----------------
// 128x128 tile, BK=64, gl_lds XOR-swizzled staging.
// Epilogue via LDS transpose: Q (x0.125) & K -> packed QKb[s][1536] coalesced;
// V -> Vt[bh*64+d][s] coalesced.
__global__ __launch_bounds__(256) void qkv_gemm(const ushort* __restrict__ Xb,
                                                const ushort* __restrict__ Wt,
                                                const float* __restrict__ bias,
                                                ushort* __restrict__ QKb,
                                                ushort* __restrict__ Vt) {
    __shared__ ushort lds[33792 / 2];             // staging 32KB | epilogue 128x132
    ushort* Ald = lds;
    ushort* Bld = lds + 128 * 64;
    int tid  = threadIdx.x;
    int wv = tid >> 6, lane = tid & 63;
    int l15 = lane & 15, quad = lane >> 4;
    int r8 = lane >> 3, cc = lane & 7;
    int wm = wv >> 1, wn = wv & 1;
    int m0 = blockIdx.x * 128, n0 = blockIdx.y * 128;

    floatx4 acc[4][4] = {};

    for (int k0 = 0; k0 < EMB; k0 += 64) {
        __syncthreads();
        for (int i = 0; i < 4; i++) {
            int row = wv * 32 + i * 8 + r8;
            int gc  = cc ^ r8;
            gl_lds16(Xb + (size_t)(m0 + row) * EMB + k0 + gc * 8,
                     (char*)Ald + (wv * 32 + i * 8) * 128);
            gl_lds16(Wt + (size_t)(n0 + row) * EMB + k0 + gc * 8,
                     (char*)Bld + (wv * 32 + i * 8) * 128);
        }
        __syncthreads();
        for (int ch = 0; ch < 2; ch++) {
            int sw = ((ch * 4 + quad) ^ (l15 & 7)) * 16;
            short8 af[4], bf[4];
            for (int mi = 0; mi < 4; mi++)
                af[mi] = *(const short8*)((const char*)Ald + (wm * 64 + mi * 16 + l15) * 128 + sw);
            for (int ni = 0; ni < 4; ni++)
                bf[ni] = *(const short8*)((const char*)Bld + (wn * 64 + ni * 16 + l15) * 128 + sw);
            for (int mi = 0; mi < 4; mi++)
                for (int ni = 0; ni < 4; ni++)
                    acc[mi][ni] = __builtin_amdgcn_mfma_f32_16x16x32_bf16(
                        af[mi], bf[ni], acc[mi][ni], 0, 0, 0);
        }
    }

    __syncthreads();  // staging reads done; lds reused for epilogue
    if (n0 < 1536) {
        // Q (scaled) / K: LDS[m][n] 2B writes, then coalesced row stores
        float scale = (n0 < 768) ? 0.125f : 1.0f;
        for (int ni = 0; ni < 4; ni++) {
            int nl = wn * 64 + ni * 16 + l15;
            float bv = bias[n0 + nl];
            for (int mi = 0; mi < 4; mi++)
                for (int r = 0; r < 4; r++) {
                    int ml = wm * 64 + mi * 16 + quad * 4 + r;
                    lds[ml * 132 + nl] = f2bf((acc[mi][ni][r] + bv) * scale);
                }
        }
        __syncthreads();
        int row = tid >> 1, half = tid & 1;
        size_t gm = (size_t)(m0 + row);
        for (int i = 0; i < 8; i++) {
            uint4 v = *(const uint4*)&lds[row * 132 + half * 64 + i * 8];
            *(uint4*)&QKb[gm * 1536 + n0 + half * 64 + i * 8] = v;
        }
    } else {
        // V: LDS[n][m] b64-packed writes, then coalesced row stores to Vt[d][s]
        for (int ni = 0; ni < 4; ni++) {
            int nl = wn * 64 + ni * 16 + l15;
            float bv = bias[n0 + nl];
            for (int mi = 0; mi < 4; mi++) {
                int ml = wm * 64 + mi * 16 + quad * 4;
                ushort4 pk4;
                pk4.x = f2bf(acc[mi][ni][0] + bv);
                pk4.y = f2bf(acc[mi][ni][1] + bv);
                pk4.z = f2bf(acc[mi][ni][2] + bv);
                pk4.w = f2bf(acc[mi][ni][3] + bv);
                *(ushort4*)&lds[nl * 132 + ml] = pk4;
            }
        }
        __syncthreads();
        int row = tid >> 1, half = tid & 1;
        int nn = n0 + row - 1536;
        int h = nn >> 6, d = nn & 63;
        int b = m0 >> 11, s0 = m0 & 2047;
        for (int i = 0; i < 8; i++) {
            uint4 v = *(const uint4*)&lds[row * 132 + half * 64 + i * 8];
            *(uint4*)&Vt[((size_t)(b * NH + h) * 64 + d) * S_LEN + s0 + half * 64 + i * 8] = v;
        }
    }
}

// ---------------- Attention: ReLU(Q K^T, causal) @ V  (Q pre-scaled) --------
// Persistent blocks + atomic queue. Per item: q-tile 128; STAGE = 128 k-cols
// (two 64-tiles) per barrier -> half the vmcnt(0) drains. Double-buffered.
__global__ __launch_bounds__(256) void attn(const ushort* __restrict__ QKb,
                                            const ushort* __restrict__ Vt,
                                            float* __restrict__ out,
                                            int* __restrict__ counter) {
    __shared__ ushort Kld[2][128 * 64];   // [s-row][d] 128B rows
    __shared__ ushort Vld[2][64 * 128];   // [d][s] 256B rows
    int* slot = (int*)&Kld[0][0];         // aliased (LDS is exactly 64KB)
    int tid = threadIdx.x;
    int w = tid >> 6, lane = tid & 63;
    int l15 = lane & 15, quad = lane >> 4;
    int r8 = lane >> 3, cc = lane & 7;

    while (true) {
        __syncthreads();                       // prior item's LDS use done
        if (tid == 0) *slot = atomicAdd(counter, 1);
        __syncthreads();
        int it = *slot;
        __syncthreads();                       // slot read before staging clobbers
        if (it >= N_ITEMS) break;
        int qt = 15 - it / 48;                 // cost-descending
        int bh = it % 48;
        int bg = bh / NH, h = bh % NH;

        const ushort* Qcol = QKb + (size_t)bg * S_LEN * 1536 + h * 64;          // q cols
        const ushort* Kcol = QKb + (size_t)bg * S_LEN * 1536 + 768 + h * 64;    // k cols
        const ushort* Vbase = Vt + (size_t)bh * HD * S_LEN;

        // Q fragments (B-operand layout), rows stride 1536
        short8 qf[2][2];
        for (int nq = 0; nq < 2; nq++)
            for (int ch = 0; ch < 2; ch++)
                qf[nq][ch] = *(const short8*)(Qcol +
                    (size_t)(qt * 128 + w * 32 + nq * 16 + l15) * 1536 + ch * 32 + quad * 8);

        floatx4 acco[2][4] = {};
        int nst = qt + 1;                      // stages of 128 k-cols

        // ---- stage 0 into buffer 0 ----
        {
            for (int i = 0; i < 4; i++) {      // K: 128 rows x 64 d
                int rK = w * 32 + i * 8;
                gl_lds16(Kcol + (size_t)(rK + r8) * 1536 + (cc ^ r8) * 8,
                         (char*)Kld[0] + rK * 128);
            }
            for (int i = 0; i < 4; i++) {      // V: 64 d-rows x 128 s
                int rV = w * 16 + i * 4;
                int rr = lane >> 4;
                int gc = (lane & 15) ^ ((i * 4 + rr) & 15);
                gl_lds16(Vbase + (size_t)(rV + rr) * S_LEN + gc * 8,
                         (char*)Vld[0] + rV * 256);
            }
        }

        int p = 0;
        for (int st_i = 0; st_i < nst; st_i++) {
            __syncthreads();                   // buf[p] staged
            if (st_i + 1 < nst) {              // prefetch next stage
                const ushort* Kc = Kcol + (size_t)(st_i + 1) * 128 * 1536;
                const ushort* Vc = Vbase + (size_t)(st_i + 1) * 128;
                for (int i = 0; i < 4; i++) {
                    int rK = w * 32 + i * 8;
                    gl_lds16(Kc + (size_t)(rK + r8) * 1536 + (cc ^ r8) * 8,
                             (char*)Kld[p ^ 1] + rK * 128);
                }
                for (int i = 0; i < 4; i++) {
                    int rV = w * 16 + i * 4;
                    int rr = lane >> 4;
                    int gc = (lane & 15) ^ ((i * 4 + rr) & 15);
                    gl_lds16(Vc + (size_t)(rV + rr) * S_LEN + gc * 8,
                             (char*)Vld[p ^ 1] + rV * 256);
                }
            }
            bool diag = (st_i == qt);

            for (int jsub = 0; jsub < 2; jsub++) {
                // S^T = K·Q^T : 64 k-rows x 32 q, K(d)=64
                floatx4 st[4][2] = {};
                for (int ch = 0; ch < 2; ch++) {
                    int sw = ((ch * 4 + quad) ^ (l15 & 7)) * 16;
                    short8 kf[4];
                    for (int mk = 0; mk < 4; mk++)
                        kf[mk] = *(const short8*)((const char*)Kld[p] +
                                  (jsub * 64 + mk * 16 + l15) * 128 + sw);
                    for (int mk = 0; mk < 4; mk++)
                        for (int nq = 0; nq < 2; nq++)
                            st[mk][nq] = __builtin_amdgcn_mfma_f32_16x16x32_bf16(
                                kf[mk], qf[nq][ch], st[mk][nq], 0, 0, 0);
                }

                // ReLU + causal mask + pack (PV A-frag layout; scale pre-folded)
                unsigned int pk[4][2][2];
                for (int mk = 0; mk < 4; mk++) {
                    for (int nq = 0; nq < 2; nq++) {
                        float e[4];
                        for (int r = 0; r < 4; r++)
                            e[r] = fmaxf(st[mk][nq][r], 0.0f);
                        if (diag) {
                            int kg = (st_i * 2 + jsub) * 64 + mk * 16 + quad * 4;
                            int qg = qt * 128 + w * 32 + nq * 16 + l15;
                            for (int r = 0; r < 4; r++)
                                if (kg + r > qg) e[r] = 0.0f;
                        }
                        pk[mk][nq][0] = pack2bf(e[0], e[1]);
                        pk[mk][nq][1] = pack2bf(e[2], e[3]);
                    }
                }

                // O += P·V via 16x16x16 (A in-register, B = V from LDS)
                for (int mk = 0; mk < 4; mk++) {
                    int u = jsub * 8 + mk * 2 + (quad >> 1);
                    short4v vf[4];
                    for (int ni = 0; ni < 4; ni++)
                        vf[ni] = *(const short4v*)((const char*)Vld[p] +
                                  (ni * 16 + l15) * 256 + (u ^ l15) * 16 + (quad & 1) * 8);
                    for (int mi = 0; mi < 2; mi++) {
                        short4v a = __builtin_bit_cast(short4v,
                                     (uint2v){pk[mk][mi][0], pk[mk][mi][1]});
                        for (int ni = 0; ni < 4; ni++)
                            acco[mi][ni] = __builtin_amdgcn_mfma_f32_16x16x16bf16_1k(
                                a, vf[ni], acco[mi][ni], 0, 0, 0);
                    }
                }
            }
            p ^= 1;
        }

        // epilogue: out[b][s][h*64+d] fp32
        for (int mi = 0; mi < 2; mi++) {
            for (int ni = 0; ni < 4; ni++) {
                int d = ni * 16 + l15;
                for (int r = 0; r < 4; r++) {
                    int s = qt * 128 + w * 32 + mi * 16 + quad * 4 + r;
                    out[((size_t)bg * S_LEN + s) * EMB + h * 64 + d] = acco[mi][ni][r];
                }
            }
        }
    }
}

extern "C" void kernel_launch(void* const* d_in, const int* in_sizes, int n_in,
                              void* d_out, int out_size, void* d_ws, size_t ws_size,
                              hipStream_t stream) {
    const float* x    = (const float*)d_in[0];   // [4,2048,768]
    const float* W    = (const float*)d_in[1];   // [768,2304]
    const float* bias = (const float*)d_in[2];   // [2304]
    float* out = (float*)d_out;                  // [4,2048,768] fp32

    char* ws = (char*)d_ws;
    const size_t SZ_X  = (size_t)8192 * EMB * 2;        // 12.6 MB
    const size_t SZ_W  = (size_t)E3 * EMB * 2;          //  3.5 MB
    const size_t SZ_QK = (size_t)8192 * 1536 * 2;       // 25.2 MB
    const size_t SZ_V  = (size_t)48 * HD * S_LEN * 2;   // 12.6 MB
    ushort* Xb  = (ushort*)(ws);
    ushort* Wt  = (ushort*)(ws + SZ_X);
    ushort* QKb = (ushort*)(ws + SZ_X + SZ_W);
    ushort* Vt  = (ushort*)(ws + SZ_X + SZ_W + SZ_QK);
    int* counter = (int*)(ws + SZ_X + SZ_W + SZ_QK + SZ_V);

    conv_fused<<<dim3(6144 + 1728), dim3(256), 0, stream>>>(x, Xb, W, Wt, counter);
    qkv_gemm<<<dim3(64, 18), dim3(256), 0, stream>>>(Xb, Wt, bias, QKb, Vt);
    attn<<<dim3(512), dim3(256), 0, stream>>>(QKb, Vt, out, counter);
}